// Round 9
// baseline (596.992 us; speedup 1.0000x reference)
//
#include <hip/hip_runtime.h>
#include <hip/hip_bf16.h>

// GraphSage: 3x SAGEConv(mean) + linear head.
// Precision: packed split-bf16 (uint32 = hi<<16|lo, val = f(hi)+f(lo)).
// GEMM: weight-stationary MFMA with GRID-STRIDE tile loop (512 blocks).
//   NOTE: the grid-stride loop is load-bearing — it forces the compiler to
//   keep the 128-VGPR B-fragment set live across tiles (round 6 regression:
//   1 tile/block -> VGPR=32, B re-read 3125x, 75us vs <55us).
// CSR count/scatter: dst-range partitioned (8 edge-chunks x 64 node ranges).
//   Round 7/8 showed the random scatter is HBM WRITE-AMPLIFICATION bound
//   (52-67MB writeback for a 1.6-3.2MB buffer): CSR slots of one node get
//   written from all 8 non-coherent XCD L2s -> repeated line writebacks.
//   Partitioning by dst range confines each perm segment to <=8 writer
//   blocks; dst stream reads are contiguous and L2-broadcast friendly.
//   (nontemporal stores REGRESSED: they bypass L2 coalescing entirely.)
// Aggregate: 1 node/wave, uint2 lanes, 16-deep gather unroll.
// Head fused into layer-2 GEMM.

constexpr int NN = 50000;
constexpr int NE = 800000;
constexpr int NCH = (NN + 255) / 256;
constexpr int NTILE = NN / 16;          // 3125 exact

constexpr int SC_CHUNKS = 8;            // edge chunks
constexpr int SC_RANGES = 64;           // node ranges
constexpr int SC_ESTEP = NE / SC_CHUNKS;            // 100000 (div by 4)
constexpr int SC_NSTEP = (NN + SC_RANGES - 1) / SC_RANGES;  // 782

using bf16x8 = __attribute__((ext_vector_type(8))) short;
using f32x4  = __attribute__((ext_vector_type(4))) float;

__device__ __forceinline__ unsigned short bf16_rne(float f) {
    unsigned u = __float_as_uint(f);
    unsigned r = (u + 0x7FFFu + ((u >> 16) & 1u)) >> 16;
    return (unsigned short)r;
}
__device__ __forceinline__ float bf16_f(unsigned short h) {
    return __uint_as_float(((unsigned)h) << 16);
}
__device__ __forceinline__ unsigned pack_split(float v) {
    unsigned short hi = bf16_rne(v);
    float r = v - bf16_f(hi);
    unsigned short lo = bf16_rne(r);
    return (((unsigned)hi) << 16) | (unsigned)lo;
}
__device__ __forceinline__ float unpack_f(unsigned p) {
    return __uint_as_float(p & 0xFFFF0000u) + __uint_as_float(p << 16);
}

// ---------------- CSR build ----------------

__global__ void k_zero_int(int* __restrict__ a, int n) {
    int i = blockIdx.x * blockDim.x + threadIdx.x;
    if (i < n) a[i] = 0;
}

// block (chunk, range): scan chunk's dst stream, count only own-range nodes
__global__ __launch_bounds__(256) void k_count_part(const int* __restrict__ ei,
                                                    int* __restrict__ cnt) {
    int chunk = blockIdx.x & (SC_CHUNKS - 1);
    int range = blockIdx.x / SC_CHUNKS;
    int lo = range * SC_NSTEP;
    int hi = lo + SC_NSTEP; if (hi > NN) hi = NN;
    int ce0 = chunk * SC_ESTEP;
    int ce1 = ce0 + SC_ESTEP;
    for (int e0 = ce0 + threadIdx.x * 4; e0 + 4 <= ce1; e0 += 1024) {
        int4 d = *(const int4*)&ei[NE + e0];
        if (d.x >= lo && d.x < hi) atomicAdd(&cnt[d.x], 1);
        if (d.y >= lo && d.y < hi) atomicAdd(&cnt[d.y], 1);
        if (d.z >= lo && d.z < hi) atomicAdd(&cnt[d.z], 1);
        if (d.w >= lo && d.w < hi) atomicAdd(&cnt[d.w], 1);
    }
}

__global__ void k_chunk_sums(const int* __restrict__ cnt, int* __restrict__ partial) {
    __shared__ int ws[4];
    int i = blockIdx.x * 256 + threadIdx.x;
    int v = (i < NN) ? cnt[i] : 0;
    for (int o = 32; o > 0; o >>= 1) v += __shfl_down(v, o);
    int lane = threadIdx.x & 63, wave = threadIdx.x >> 6;
    if (lane == 0) ws[wave] = v;
    __syncthreads();
    if (threadIdx.x == 0) partial[blockIdx.x] = ws[0] + ws[1] + ws[2] + ws[3];
}

__global__ void k_scan_partials(int* __restrict__ partial, int n) {
    __shared__ int ws[4];
    int t = threadIdx.x;
    int orig = (t < n) ? partial[t] : 0;
    int v = orig;
    int lane = t & 63, wave = t >> 6;
    for (int o = 1; o < 64; o <<= 1) { int u = __shfl_up(v, o); if (lane >= o) v += u; }
    if (lane == 63) ws[wave] = v;
    __syncthreads();
    int off = 0;
    for (int w = 0; w < 4; ++w) if (w < wave) off += ws[w];
    if (t < n) partial[t] = v + off - orig;
}

__global__ void k_scan_chunks(const int* __restrict__ cnt, const int* __restrict__ partial,
                              int* __restrict__ cursor) {
    __shared__ int ws[4];
    int i = blockIdx.x * 256 + threadIdx.x;
    int orig = (i < NN) ? cnt[i] : 0;
    int v = orig;
    int lane = threadIdx.x & 63, wave = threadIdx.x >> 6;
    for (int o = 1; o < 64; o <<= 1) { int u = __shfl_up(v, o); if (lane >= o) v += u; }
    if (lane == 63) ws[wave] = v;
    __syncthreads();
    int off = partial[blockIdx.x];
    for (int w = 0; w < 4; ++w) if (w < wave) off += ws[w];
    if (i < NN) cursor[i] = v - orig + off;
}

// block (chunk, range): scan chunk's dst, scatter only own-range edges.
// perm segment of a range is written by <= SC_CHUNKS blocks -> low writeback.
__global__ __launch_bounds__(256) void k_scatter_part(const int* __restrict__ ei,
                                                      int* __restrict__ cursor,
                                                      unsigned short* __restrict__ perm) {
    int chunk = blockIdx.x & (SC_CHUNKS - 1);
    int range = blockIdx.x / SC_CHUNKS;
    int lo = range * SC_NSTEP;
    int hi = lo + SC_NSTEP; if (hi > NN) hi = NN;
    int ce0 = chunk * SC_ESTEP;
    int ce1 = ce0 + SC_ESTEP;
    for (int e0 = ce0 + threadIdx.x * 4; e0 + 4 <= ce1; e0 += 1024) {
        int4 d = *(const int4*)&ei[NE + e0];
        if (d.x >= lo && d.x < hi) { int pos = atomicAdd(&cursor[d.x], 1); perm[pos] = (unsigned short)ei[e0 + 0]; }
        if (d.y >= lo && d.y < hi) { int pos = atomicAdd(&cursor[d.y], 1); perm[pos] = (unsigned short)ei[e0 + 1]; }
        if (d.z >= lo && d.z < hi) { int pos = atomicAdd(&cursor[d.z], 1); perm[pos] = (unsigned short)ei[e0 + 2]; }
        if (d.w >= lo && d.w < hi) { int pos = atomicAdd(&cursor[d.w], 1); perm[pos] = (unsigned short)ei[e0 + 3]; }
    }
}

// ---------------- packing ----------------

__global__ void k_pack_x(const float* __restrict__ x, unsigned* __restrict__ xp) {
    int i = blockIdx.x * blockDim.x + threadIdx.x;
    constexpr int TOT = NN * 128 / 4;
    if (i < TOT) {
        float4 v = ((const float4*)x)[i];
        uint4 o;
        o.x = pack_split(v.x); o.y = pack_split(v.y);
        o.z = pack_split(v.z); o.w = pack_split(v.w);
        ((uint4*)xp)[i] = o;
    }
}

// Wl,Wr [128 out][128 in] fp32 -> combined hi/lo bf16 planes [128 c][256 k]
__global__ void k_pack_w(const float* __restrict__ Wl, const float* __restrict__ Wr,
                         unsigned short* __restrict__ whi, unsigned short* __restrict__ wlo) {
    int i = blockIdx.x * blockDim.x + threadIdx.x;
    if (i < 128 * 256) {
        int c = i >> 8;
        int k = i & 255;
        float v = (k < 128) ? Wl[c * 128 + k] : Wr[c * 128 + (k - 128)];
        unsigned short hi = bf16_rne(v);
        whi[i] = hi;
        wlo[i] = bf16_rne(v - bf16_f(hi));
    }
}

__global__ void k_init_out(float* __restrict__ out, const float* __restrict__ bf) {
    int i = blockIdx.x * blockDim.x + threadIdx.x;
    if (i < NN) out[i] = bf[0];
}

// ---------------- aggregate (mean over CSR neighbors) ----------------
// one wave per node; lane l holds cols [2l, 2l+1] (packed uint2).
// 16-deep unroll -> 16 outstanding 512B row gathers (8KB in flight/wave).
__global__ __launch_bounds__(256) void k_aggregate(const unsigned* __restrict__ hp,
        const int* __restrict__ cursor, const int* __restrict__ cnt,
        const unsigned short* __restrict__ perm, unsigned* __restrict__ outp) {
    int wave = __builtin_amdgcn_readfirstlane(threadIdx.x >> 6);
    int lane = threadIdx.x & 63;
    int node = blockIdx.x * 4 + wave;
    if (node >= NN) return;
    int deg = cnt[node];
    int start = cursor[node] - deg;
    const uint2* base = (const uint2*)hp;    // row stride = 64 uint2
    float ax = 0.f, ay = 0.f;
    int j = 0;
    for (; j + 16 <= deg; j += 16) {
        int s[16];
#pragma unroll
        for (int u = 0; u < 16; ++u) s[u] = perm[start + j + u];
        uint2 q[16];
#pragma unroll
        for (int u = 0; u < 16; ++u) q[u] = base[(size_t)s[u] * 64 + lane];
#pragma unroll
        for (int u = 0; u < 16; ++u) { ax += unpack_f(q[u].x); ay += unpack_f(q[u].y); }
    }
    for (; j + 4 <= deg; j += 4) {
        int s[4];
#pragma unroll
        for (int u = 0; u < 4; ++u) s[u] = perm[start + j + u];
        uint2 q[4];
#pragma unroll
        for (int u = 0; u < 4; ++u) q[u] = base[(size_t)s[u] * 64 + lane];
#pragma unroll
        for (int u = 0; u < 4; ++u) { ax += unpack_f(q[u].x); ay += unpack_f(q[u].y); }
    }
    for (; j < deg; ++j) {
        int s = perm[start + j];
        uint2 q = base[(size_t)s * 64 + lane];
        ax += unpack_f(q.x);
        ay += unpack_f(q.y);
    }
    float inv = 1.0f / (float)(deg > 1 ? deg : 1);
    uint2 o;
    o.x = pack_split(ax * inv);
    o.y = pack_split(ay * inv);
    ((uint2*)(outp + (size_t)node * 128))[lane] = o;
}

// ---------------- weight-stationary MFMA GEMM (grid-stride) ----------------
// out[n][c] = relu( bias[c] + sum_k [A0|A1][n][k] W[c][k] )
// Wave w owns cols [32w,32w+32): B hi/lo frags hoisted to 128 VGPRs once,
// live across the tile loop. In-place safe: each tile owned by one block;
// __syncthreads() between the block's reads and writes of its rows.
__global__ __launch_bounds__(256, 2) void k_gemm_ws(
        const unsigned* __restrict__ A0p, const unsigned* __restrict__ A1p,
        const unsigned short* __restrict__ Whi, const unsigned short* __restrict__ Wlo,
        const float* __restrict__ bias, unsigned* __restrict__ outp) {
    int wave = __builtin_amdgcn_readfirstlane(threadIdx.x >> 6);
    int lane = threadIdx.x & 63;
    int row = lane & 15;        // A row in tile / D col in ct-tile
    int kb = lane >> 4;         // k-subblock 0..3
    int ct0 = wave * 2;

    bf16x8 bh[2][8], bl[2][8];
#pragma unroll
    for (int c = 0; c < 2; ++c)
#pragma unroll
        for (int kc = 0; kc < 8; ++kc) {
            size_t widx = (size_t)((ct0 + c) * 16 + row) * 256 + kc * 32 + kb * 8;
            bh[c][kc] = *(const bf16x8*)(Whi + widx);
            bl[c][kc] = *(const bf16x8*)(Wlo + widx);
        }
    float b0 = bias[ct0 * 16 + row];
    float b1 = bias[ct0 * 16 + 16 + row];

    for (int t = blockIdx.x; t < NTILE; t += gridDim.x) {
        int n0 = t * 16;
        const unsigned* a0 = A0p + (size_t)(n0 + row) * 128 + kb * 8;
        const unsigned* a1 = A1p + (size_t)(n0 + row) * 128 + kb * 8;
        f32x4 acc0 = {0.f, 0.f, 0.f, 0.f};
        f32x4 acc1 = {0.f, 0.f, 0.f, 0.f};
#pragma unroll
        for (int kc = 0; kc < 8; ++kc) {
            const unsigned* ap = ((kc < 4) ? a0 : a1) + (kc & 3) * 32;
            uint4 q0 = *(const uint4*)ap;
            uint4 q1 = *(const uint4*)(ap + 4);
            unsigned pk[8] = {q0.x, q0.y, q0.z, q0.w, q1.x, q1.y, q1.z, q1.w};
            bf16x8 ah, al;
#pragma unroll
            for (int j = 0; j < 8; ++j) {
                ah[j] = (short)(pk[j] >> 16);
                al[j] = (short)(pk[j] & 0xFFFFu);
            }
            acc0 = __builtin_amdgcn_mfma_f32_16x16x32_bf16(ah, bh[0][kc], acc0, 0, 0, 0);
            acc0 = __builtin_amdgcn_mfma_f32_16x16x32_bf16(al, bh[0][kc], acc0, 0, 0, 0);
            acc0 = __builtin_amdgcn_mfma_f32_16x16x32_bf16(ah, bl[0][kc], acc0, 0, 0, 0);
            acc1 = __builtin_amdgcn_mfma_f32_16x16x32_bf16(ah, bh[1][kc], acc1, 0, 0, 0);
            acc1 = __builtin_amdgcn_mfma_f32_16x16x32_bf16(al, bh[1][kc], acc1, 0, 0, 0);
            acc1 = __builtin_amdgcn_mfma_f32_16x16x32_bf16(ah, bl[1][kc], acc1, 0, 0, 0);
        }
        __syncthreads();   // all waves' reads of this tile's rows precede writes
        int cb0 = ct0 * 16 + row;
#pragma unroll
        for (int r = 0; r < 4; ++r) {
            int n = n0 + kb * 4 + r;         // D: col=lane&15, row=(lane>>4)*4+reg
            unsigned* orow = outp + (size_t)n * 128;
            orow[cb0]      = pack_split(fmaxf(acc0[r] + b0, 0.f));
            orow[cb0 + 16] = pack_split(fmaxf(acc1[r] + b1, 0.f));
        }
    }
}

// layer-2 variant: head fused — out[n] += sum_c relu(h3[n][c]) * Wf[c]
__global__ __launch_bounds__(256, 2) void k_gemm_head(
        const unsigned* __restrict__ A0p, const unsigned* __restrict__ A1p,
        const unsigned short* __restrict__ Whi, const unsigned short* __restrict__ Wlo,
        const float* __restrict__ bias, const float* __restrict__ Wf,
        float* __restrict__ out) {
    int wave = __builtin_amdgcn_readfirstlane(threadIdx.x >> 6);
    int lane = threadIdx.x & 63;
    int row = lane & 15;
    int kb = lane >> 4;
    int ct0 = wave * 2;

    bf16x8 bh[2][8], bl[2][8];
#pragma unroll
    for (int c = 0; c < 2; ++c)
#pragma unroll
        for (int kc = 0; kc < 8; ++kc) {
            size_t widx = (size_t)((ct0 + c) * 16 + row) * 256 + kc * 32 + kb * 8;
            bh[c][kc] = *(const bf16x8*)(Whi + widx);
            bl[c][kc] = *(const bf16x8*)(Wlo + widx);
        }
    float b0 = bias[ct0 * 16 + row];
    float b1 = bias[ct0 * 16 + 16 + row];
    float w0 = Wf[ct0 * 16 + row];
    float w1 = Wf[ct0 * 16 + 16 + row];

    for (int t = blockIdx.x; t < NTILE; t += gridDim.x) {
        int n0 = t * 16;
        const unsigned* a0 = A0p + (size_t)(n0 + row) * 128 + kb * 8;
        const unsigned* a1 = A1p + (size_t)(n0 + row) * 128 + kb * 8;
        f32x4 acc0 = {0.f, 0.f, 0.f, 0.f};
        f32x4 acc1 = {0.f, 0.f, 0.f, 0.f};
#pragma unroll
        for (int kc = 0; kc < 8; ++kc) {
            const unsigned* ap = ((kc < 4) ? a0 : a1) + (kc & 3) * 32;
            uint4 q0 = *(const uint4*)ap;
            uint4 q1 = *(const uint4*)(ap + 4);
            unsigned pk[8] = {q0.x, q0.y, q0.z, q0.w, q1.x, q1.y, q1.z, q1.w};
            bf16x8 ah, al;
#pragma unroll
            for (int j = 0; j < 8; ++j) {
                ah[j] = (short)(pk[j] >> 16);
                al[j] = (short)(pk[j] & 0xFFFFu);
            }
            acc0 = __builtin_amdgcn_mfma_f32_16x16x32_bf16(ah, bh[0][kc], acc0, 0, 0, 0);
            acc0 = __builtin_amdgcn_mfma_f32_16x16x32_bf16(al, bh[0][kc], acc0, 0, 0, 0);
            acc0 = __builtin_amdgcn_mfma_f32_16x16x32_bf16(ah, bl[0][kc], acc0, 0, 0, 0);
            acc1 = __builtin_amdgcn_mfma_f32_16x16x32_bf16(ah, bh[1][kc], acc1, 0, 0, 0);
            acc1 = __builtin_amdgcn_mfma_f32_16x16x32_bf16(al, bh[1][kc], acc1, 0, 0, 0);
            acc1 = __builtin_amdgcn_mfma_f32_16x16x32_bf16(ah, bl[1][kc], acc1, 0, 0, 0);
        }
        float part[4];
#pragma unroll
        for (int r = 0; r < 4; ++r)
            part[r] = fmaxf(acc0[r] + b0, 0.f) * w0 + fmaxf(acc1[r] + b1, 0.f) * w1;
#pragma unroll
        for (int o = 1; o < 16; o <<= 1) {
#pragma unroll
            for (int r = 0; r < 4; ++r) part[r] += __shfl_xor(part[r], o);
        }
        if (row == 0) {
#pragma unroll
            for (int r = 0; r < 4; ++r) atomicAdd(&out[n0 + kb * 4 + r], part[r]);
        }
    }
}

extern "C" void kernel_launch(void* const* d_in, const int* in_sizes, int n_in,
                              void* d_out, int out_size, void* d_ws, size_t ws_size,
                              hipStream_t stream) {
    const float* x   = (const float*)d_in[0];
    const int*   ei  = (const int*)d_in[1];
    const float* Wl0 = (const float*)d_in[2];
    const float* bl0 = (const float*)d_in[3];
    const float* Wr0 = (const float*)d_in[4];
    const float* Wl1 = (const float*)d_in[5];
    const float* bl1 = (const float*)d_in[6];
    const float* Wr1 = (const float*)d_in[7];
    const float* Wl2 = (const float*)d_in[8];
    const float* bl2 = (const float*)d_in[9];
    const float* Wr2 = (const float*)d_in[10];
    const float* Wf  = (const float*)d_in[11];
    const float* bf  = (const float*)d_in[12];
    float* out = (float*)d_out;

    char* p = (char*)d_ws;
    auto alloc = [&](size_t n) { void* r = (void*)p; p += (n + 255) & ~(size_t)255; return r; };
    int*            cnt     = (int*)alloc((size_t)NN * 4);
    int*            cursor  = (int*)alloc((size_t)NN * 4);
    int*            partial = (int*)alloc(256 * 4);
    unsigned short* perm    = (unsigned short*)alloc((size_t)NE * 2);
    unsigned*       sbuf    = (unsigned*)alloc((size_t)NN * 128 * 4);
    unsigned*       hp      = (unsigned*)alloc((size_t)NN * 128 * 4);
    unsigned short* whi     = (unsigned short*)alloc((size_t)3 * 128 * 256 * 2);
    unsigned short* wlo     = (unsigned short*)alloc((size_t)3 * 128 * 256 * 2);

    dim3 b256(256);
    // CSR build (dst-range partitioned count + scatter)
    k_zero_int<<<dim3((NN + 255) / 256), b256, 0, stream>>>(cnt, NN);
    k_count_part<<<dim3(SC_CHUNKS * SC_RANGES), b256, 0, stream>>>(ei, cnt);
    k_chunk_sums<<<dim3(NCH), b256, 0, stream>>>(cnt, partial);
    k_scan_partials<<<dim3(1), b256, 0, stream>>>(partial, NCH);
    k_scan_chunks<<<dim3(NCH), b256, 0, stream>>>(cnt, partial, cursor);
    k_scatter_part<<<dim3(SC_CHUNKS * SC_RANGES), b256, 0, stream>>>(ei, cursor, perm);

    // packing + out init
    k_pack_x<<<dim3((NN * 128 / 4 + 255) / 256), b256, 0, stream>>>(x, hp);
    k_pack_w<<<dim3(128), b256, 0, stream>>>(Wl0, Wr0, whi + 0 * 32768, wlo + 0 * 32768);
    k_pack_w<<<dim3(128), b256, 0, stream>>>(Wl1, Wr1, whi + 1 * 32768, wlo + 1 * 32768);
    k_pack_w<<<dim3(128), b256, 0, stream>>>(Wl2, Wr2, whi + 2 * 32768, wlo + 2 * 32768);
    k_init_out<<<dim3((NN + 255) / 256), b256, 0, stream>>>(out, bf);

    dim3 gAgg((NN + 3) / 4);    // 1 node/wave, 4 per block
    dim3 gGemm(512);            // 2 blocks/CU; grid-stride over 3125 tiles

    // layer 0
    k_aggregate<<<gAgg, b256, 0, stream>>>(hp, cursor, cnt, perm, sbuf);
    k_gemm_ws<<<gGemm, b256, 0, stream>>>(sbuf, hp, whi + 0 * 32768, wlo + 0 * 32768, bl0, hp);
    // layer 1 (in place)
    k_aggregate<<<gAgg, b256, 0, stream>>>(hp, cursor, cnt, perm, sbuf);
    k_gemm_ws<<<gGemm, b256, 0, stream>>>(sbuf, hp, whi + 1 * 32768, wlo + 1 * 32768, bl1, hp);
    // layer 2 + fused head
    k_aggregate<<<gAgg, b256, 0, stream>>>(hp, cursor, cnt, perm, sbuf);
    k_gemm_head<<<gGemm, b256, 0, stream>>>(sbuf, hp, whi + 2 * 32768, wlo + 2 * 32768, bl2, Wf, out);
}

// Round 10
// 414.443 us; speedup vs baseline: 1.4405x; 1.4405x over previous
//
#include <hip/hip_runtime.h>
#include <hip/hip_bf16.h>

// GraphSage: 3x SAGEConv(mean) + linear head.
// Precision: packed split-bf16 (uint32 = hi<<16|lo, val = f(hi)+f(lo)).
// GEMM: weight-stationary MFMA with GRID-STRIDE tile loop (512 blocks).
//   NOTE: the grid-stride loop is load-bearing — it forces the compiler to
//   keep the 128-VGPR B-fragment set live across tiles (round 6 regression:
//   1 tile/block -> VGPR=32, B re-read 3125x, 75us vs <55us).
// CSR build: two-level MSD bucket sort — NO random global scatter.
//   History: plain atomic-cursor scatter = 57us (WRITE_SIZE 53MB for a 3MB
//   buffer: cross-XCD line ping-pong); nontemporal = worse (67MB); dst-range
//   partitioned scan = 175us (64x redundant reads). Fix: (1) per-block LDS
//   histogram of dst>>8, (2) base scan, (3) rank-scatter into block-private
//   contiguous regions (packed u32 recs), (4) one block per bucket builds the
//   256-node sub-CSR entirely in LDS, writes perm/cnt/row_start coalesced.
//   Stability not needed: within one dst any neighbor order is valid (mean).
// Aggregate: 1 node/wave, uint2 lanes, 16-deep gather unroll.
// Head fused into layer-2 GEMM. packed[] aliases sbuf[] (disjoint lifetime).

constexpr int NN = 50000;
constexpr int NE = 800000;
constexpr int NTILE = NN / 16;          // 3125 exact
constexpr int EPB = 4096;               // edges per sort block
constexpr int NBLK = (NE + EPB - 1) / EPB;   // 196
constexpr int NBUCK = 196;              // dst>>8 < 196 (dst < 50000)
constexpr int BCAP = 6144;              // bucket capacity (mean 4096, sd ~64)

using bf16x8 = __attribute__((ext_vector_type(8))) short;
using f32x4  = __attribute__((ext_vector_type(4))) float;

__device__ __forceinline__ unsigned short bf16_rne(float f) {
    unsigned u = __float_as_uint(f);
    unsigned r = (u + 0x7FFFu + ((u >> 16) & 1u)) >> 16;
    return (unsigned short)r;
}
__device__ __forceinline__ float bf16_f(unsigned short h) {
    return __uint_as_float(((unsigned)h) << 16);
}
__device__ __forceinline__ unsigned pack_split(float v) {
    unsigned short hi = bf16_rne(v);
    float r = v - bf16_f(hi);
    unsigned short lo = bf16_rne(r);
    return (((unsigned)hi) << 16) | (unsigned)lo;
}
__device__ __forceinline__ float unpack_f(unsigned p) {
    return __uint_as_float(p & 0xFFFF0000u) + __uint_as_float(p << 16);
}

// ---------------- CSR build (bucket sort) ----------------

// per-block LDS histogram of dst>>8
__global__ __launch_bounds__(256) void k_hist(const int* __restrict__ ei,
                                              int* __restrict__ hist) {
    __shared__ int h[256];
    h[threadIdx.x] = 0;
    __syncthreads();
    int e0 = blockIdx.x * EPB;
    int e1 = e0 + EPB; if (e1 > NE) e1 = NE;
    for (int e = e0 + threadIdx.x; e < e1; e += 256)
        atomicAdd(&h[ei[NE + e] >> 8], 1);
    __syncthreads();
    hist[blockIdx.x * 256 + threadIdx.x] = h[threadIdx.x];
}

// single block: hist[blk][b] -> block-relative base; dbase[b] = bucket base.
// After this kernel hist[blk][b] = absolute write base for (blk, bucket b).
__global__ __launch_bounds__(256) void k_basescan(int* __restrict__ hist,
                                                  int* __restrict__ dbase) {
    __shared__ int ws[4];
    int b = threadIdx.x;
    int run = 0;
    for (int blk = 0; blk + 4 <= NBLK; blk += 4) {   // NBLK = 196 = 4*49
        int v0 = hist[(blk + 0) * 256 + b];
        int v1 = hist[(blk + 1) * 256 + b];
        int v2 = hist[(blk + 2) * 256 + b];
        int v3 = hist[(blk + 3) * 256 + b];
        hist[(blk + 0) * 256 + b] = run;
        hist[(blk + 1) * 256 + b] = run + v0;
        hist[(blk + 2) * 256 + b] = run + v0 + v1;
        hist[(blk + 3) * 256 + b] = run + v0 + v1 + v2;
        run += v0 + v1 + v2 + v3;
    }
    // exclusive scan of per-bucket totals across 256 threads
    int lane = b & 63, wave = b >> 6;
    int orig = run, v = run;
    for (int o = 1; o < 64; o <<= 1) { int u = __shfl_up(v, o); if (lane >= o) v += u; }
    if (lane == 63) ws[wave] = v;
    __syncthreads();
    int off = 0;
    for (int w = 0; w < wave; ++w) off += ws[w];
    int binbase = v + off - orig;
    dbase[b] = binbase;           // dbase[196] == NE (bins >=196 empty)
    for (int blk = 0; blk < NBLK; ++blk) hist[blk * 256 + b] += binbase;
}

// rank-scatter: block writes each bucket's records to its private region
__global__ __launch_bounds__(256) void k_scatter1(const int* __restrict__ ei,
                                                  const int* __restrict__ hist,
                                                  unsigned* __restrict__ packed) {
    __shared__ int cur[256];
    cur[threadIdx.x] = hist[blockIdx.x * 256 + threadIdx.x];
    __syncthreads();
    int e0 = blockIdx.x * EPB;
    int e1 = e0 + EPB; if (e1 > NE) e1 = NE;
    for (int e = e0 + threadIdx.x; e < e1; e += 256) {
        int s = ei[e];
        int d = ei[NE + e];
        int pos = atomicAdd(&cur[d >> 8], 1);
        packed[pos] = ((unsigned)d << 16) | (unsigned)s;
    }
}

// one block per bucket: build 256-node sub-CSR in LDS, write coalesced
__global__ __launch_bounds__(256) void k_bucket_csr(const unsigned* __restrict__ packed,
        const int* __restrict__ dbase, unsigned short* __restrict__ perm,
        int* __restrict__ cnt, int* __restrict__ row_start) {
    __shared__ unsigned recs[BCAP];
    __shared__ unsigned short outs[BCAP];
    __shared__ int cntL[256], startL[256];
    __shared__ int ws[4];
    int b = blockIdx.x;
    int lo = dbase[b];
    int m = dbase[b + 1] - lo;
    if (m > BCAP) m = BCAP;      // unreachable for this input (16-sigma)
    int t = threadIdx.x;
    cntL[t] = 0;
    __syncthreads();
    for (int i = t; i < m; i += 256) {
        unsigned r = packed[lo + i];
        recs[i] = r;
        atomicAdd(&cntL[(r >> 16) & 255], 1);
    }
    __syncthreads();
    int lane = t & 63, wave = t >> 6;
    int orig = cntL[t], v = orig;
    for (int o = 1; o < 64; o <<= 1) { int u = __shfl_up(v, o); if (lane >= o) v += u; }
    if (lane == 63) ws[wave] = v;
    __syncthreads();
    int off = 0;
    for (int w = 0; w < wave; ++w) off += ws[w];
    int st = v + off - orig;     // exclusive local start
    startL[t] = st;
    int node = b * 256 + t;
    if (node < NN) { cnt[node] = orig; row_start[node] = lo + st; }
    __syncthreads();
    cntL[t] = st;                // reuse as local cursor
    __syncthreads();
    for (int i = t; i < m; i += 256) {
        unsigned r = recs[i];
        int pos = atomicAdd(&cntL[(r >> 16) & 255], 1);
        outs[pos] = (unsigned short)(r & 0xFFFFu);
    }
    __syncthreads();
    for (int i = t; i < m; i += 256)
        perm[lo + i] = outs[i];
}

// ---------------- packing ----------------

__global__ void k_pack_x(const float* __restrict__ x, unsigned* __restrict__ xp) {
    int i = blockIdx.x * blockDim.x + threadIdx.x;
    constexpr int TOT = NN * 128 / 4;
    if (i < TOT) {
        float4 v = ((const float4*)x)[i];
        uint4 o;
        o.x = pack_split(v.x); o.y = pack_split(v.y);
        o.z = pack_split(v.z); o.w = pack_split(v.w);
        ((uint4*)xp)[i] = o;
    }
}

// Wl,Wr [128 out][128 in] fp32 -> combined hi/lo bf16 planes [128 c][256 k]
__global__ void k_pack_w(const float* __restrict__ Wl, const float* __restrict__ Wr,
                         unsigned short* __restrict__ whi, unsigned short* __restrict__ wlo) {
    int i = blockIdx.x * blockDim.x + threadIdx.x;
    if (i < 128 * 256) {
        int c = i >> 8;
        int k = i & 255;
        float v = (k < 128) ? Wl[c * 128 + k] : Wr[c * 128 + (k - 128)];
        unsigned short hi = bf16_rne(v);
        whi[i] = hi;
        wlo[i] = bf16_rne(v - bf16_f(hi));
    }
}

__global__ void k_init_out(float* __restrict__ out, const float* __restrict__ bf) {
    int i = blockIdx.x * blockDim.x + threadIdx.x;
    if (i < NN) out[i] = bf[0];
}

// ---------------- aggregate (mean over CSR neighbors) ----------------
// one wave per node; lane l holds cols [2l, 2l+1] (packed uint2).
// 16-deep unroll -> 16 outstanding 512B row gathers (8KB in flight/wave).
__global__ __launch_bounds__(256) void k_aggregate(const unsigned* __restrict__ hp,
        const int* __restrict__ row_start, const int* __restrict__ cnt,
        const unsigned short* __restrict__ perm, unsigned* __restrict__ outp) {
    int wave = __builtin_amdgcn_readfirstlane(threadIdx.x >> 6);
    int lane = threadIdx.x & 63;
    int node = blockIdx.x * 4 + wave;
    if (node >= NN) return;
    int deg = cnt[node];
    int start = row_start[node];
    const uint2* base = (const uint2*)hp;    // row stride = 64 uint2
    float ax = 0.f, ay = 0.f;
    int j = 0;
    for (; j + 16 <= deg; j += 16) {
        int s[16];
#pragma unroll
        for (int u = 0; u < 16; ++u) s[u] = perm[start + j + u];
        uint2 q[16];
#pragma unroll
        for (int u = 0; u < 16; ++u) q[u] = base[(size_t)s[u] * 64 + lane];
#pragma unroll
        for (int u = 0; u < 16; ++u) { ax += unpack_f(q[u].x); ay += unpack_f(q[u].y); }
    }
    for (; j + 4 <= deg; j += 4) {
        int s[4];
#pragma unroll
        for (int u = 0; u < 4; ++u) s[u] = perm[start + j + u];
        uint2 q[4];
#pragma unroll
        for (int u = 0; u < 4; ++u) q[u] = base[(size_t)s[u] * 64 + lane];
#pragma unroll
        for (int u = 0; u < 4; ++u) { ax += unpack_f(q[u].x); ay += unpack_f(q[u].y); }
    }
    for (; j < deg; ++j) {
        int s = perm[start + j];
        uint2 q = base[(size_t)s * 64 + lane];
        ax += unpack_f(q.x);
        ay += unpack_f(q.y);
    }
    float inv = 1.0f / (float)(deg > 1 ? deg : 1);
    uint2 o;
    o.x = pack_split(ax * inv);
    o.y = pack_split(ay * inv);
    ((uint2*)(outp + (size_t)node * 128))[lane] = o;
}

// ---------------- weight-stationary MFMA GEMM (grid-stride) ----------------
// out[n][c] = relu( bias[c] + sum_k [A0|A1][n][k] W[c][k] )
// Wave w owns cols [32w,32w+32): B hi/lo frags hoisted to 128 VGPRs once,
// live across the tile loop. In-place safe: each tile owned by one block;
// __syncthreads() between the block's reads and writes of its rows.
__global__ __launch_bounds__(256, 2) void k_gemm_ws(
        const unsigned* __restrict__ A0p, const unsigned* __restrict__ A1p,
        const unsigned short* __restrict__ Whi, const unsigned short* __restrict__ Wlo,
        const float* __restrict__ bias, unsigned* __restrict__ outp) {
    int wave = __builtin_amdgcn_readfirstlane(threadIdx.x >> 6);
    int lane = threadIdx.x & 63;
    int row = lane & 15;        // A row in tile / D col in ct-tile
    int kb = lane >> 4;         // k-subblock 0..3
    int ct0 = wave * 2;

    bf16x8 bh[2][8], bl[2][8];
#pragma unroll
    for (int c = 0; c < 2; ++c)
#pragma unroll
        for (int kc = 0; kc < 8; ++kc) {
            size_t widx = (size_t)((ct0 + c) * 16 + row) * 256 + kc * 32 + kb * 8;
            bh[c][kc] = *(const bf16x8*)(Whi + widx);
            bl[c][kc] = *(const bf16x8*)(Wlo + widx);
        }
    float b0 = bias[ct0 * 16 + row];
    float b1 = bias[ct0 * 16 + 16 + row];

    for (int t = blockIdx.x; t < NTILE; t += gridDim.x) {
        int n0 = t * 16;
        const unsigned* a0 = A0p + (size_t)(n0 + row) * 128 + kb * 8;
        const unsigned* a1 = A1p + (size_t)(n0 + row) * 128 + kb * 8;
        f32x4 acc0 = {0.f, 0.f, 0.f, 0.f};
        f32x4 acc1 = {0.f, 0.f, 0.f, 0.f};
#pragma unroll
        for (int kc = 0; kc < 8; ++kc) {
            const unsigned* ap = ((kc < 4) ? a0 : a1) + (kc & 3) * 32;
            uint4 q0 = *(const uint4*)ap;
            uint4 q1 = *(const uint4*)(ap + 4);
            unsigned pk[8] = {q0.x, q0.y, q0.z, q0.w, q1.x, q1.y, q1.z, q1.w};
            bf16x8 ah, al;
#pragma unroll
            for (int j = 0; j < 8; ++j) {
                ah[j] = (short)(pk[j] >> 16);
                al[j] = (short)(pk[j] & 0xFFFFu);
            }
            acc0 = __builtin_amdgcn_mfma_f32_16x16x32_bf16(ah, bh[0][kc], acc0, 0, 0, 0);
            acc0 = __builtin_amdgcn_mfma_f32_16x16x32_bf16(al, bh[0][kc], acc0, 0, 0, 0);
            acc0 = __builtin_amdgcn_mfma_f32_16x16x32_bf16(ah, bl[0][kc], acc0, 0, 0, 0);
            acc1 = __builtin_amdgcn_mfma_f32_16x16x32_bf16(ah, bh[1][kc], acc1, 0, 0, 0);
            acc1 = __builtin_amdgcn_mfma_f32_16x16x32_bf16(al, bh[1][kc], acc1, 0, 0, 0);
            acc1 = __builtin_amdgcn_mfma_f32_16x16x32_bf16(ah, bl[1][kc], acc1, 0, 0, 0);
        }
        __syncthreads();   // all waves' reads of this tile's rows precede writes
        int cb0 = ct0 * 16 + row;
#pragma unroll
        for (int r = 0; r < 4; ++r) {
            int n = n0 + kb * 4 + r;         // D: col=lane&15, row=(lane>>4)*4+reg
            unsigned* orow = outp + (size_t)n * 128;
            orow[cb0]      = pack_split(fmaxf(acc0[r] + b0, 0.f));
            orow[cb0 + 16] = pack_split(fmaxf(acc1[r] + b1, 0.f));
        }
    }
}

// layer-2 variant: head fused — out[n] += sum_c relu(h3[n][c]) * Wf[c]
__global__ __launch_bounds__(256, 2) void k_gemm_head(
        const unsigned* __restrict__ A0p, const unsigned* __restrict__ A1p,
        const unsigned short* __restrict__ Whi, const unsigned short* __restrict__ Wlo,
        const float* __restrict__ bias, const float* __restrict__ Wf,
        float* __restrict__ out) {
    int wave = __builtin_amdgcn_readfirstlane(threadIdx.x >> 6);
    int lane = threadIdx.x & 63;
    int row = lane & 15;
    int kb = lane >> 4;
    int ct0 = wave * 2;

    bf16x8 bh[2][8], bl[2][8];
#pragma unroll
    for (int c = 0; c < 2; ++c)
#pragma unroll
        for (int kc = 0; kc < 8; ++kc) {
            size_t widx = (size_t)((ct0 + c) * 16 + row) * 256 + kc * 32 + kb * 8;
            bh[c][kc] = *(const bf16x8*)(Whi + widx);
            bl[c][kc] = *(const bf16x8*)(Wlo + widx);
        }
    float b0 = bias[ct0 * 16 + row];
    float b1 = bias[ct0 * 16 + 16 + row];
    float w0 = Wf[ct0 * 16 + row];
    float w1 = Wf[ct0 * 16 + 16 + row];

    for (int t = blockIdx.x; t < NTILE; t += gridDim.x) {
        int n0 = t * 16;
        const unsigned* a0 = A0p + (size_t)(n0 + row) * 128 + kb * 8;
        const unsigned* a1 = A1p + (size_t)(n0 + row) * 128 + kb * 8;
        f32x4 acc0 = {0.f, 0.f, 0.f, 0.f};
        f32x4 acc1 = {0.f, 0.f, 0.f, 0.f};
#pragma unroll
        for (int kc = 0; kc < 8; ++kc) {
            const unsigned* ap = ((kc < 4) ? a0 : a1) + (kc & 3) * 32;
            uint4 q0 = *(const uint4*)ap;
            uint4 q1 = *(const uint4*)(ap + 4);
            unsigned pk[8] = {q0.x, q0.y, q0.z, q0.w, q1.x, q1.y, q1.z, q1.w};
            bf16x8 ah, al;
#pragma unroll
            for (int j = 0; j < 8; ++j) {
                ah[j] = (short)(pk[j] >> 16);
                al[j] = (short)(pk[j] & 0xFFFFu);
            }
            acc0 = __builtin_amdgcn_mfma_f32_16x16x32_bf16(ah, bh[0][kc], acc0, 0, 0, 0);
            acc0 = __builtin_amdgcn_mfma_f32_16x16x32_bf16(al, bh[0][kc], acc0, 0, 0, 0);
            acc0 = __builtin_amdgcn_mfma_f32_16x16x32_bf16(ah, bl[0][kc], acc0, 0, 0, 0);
            acc1 = __builtin_amdgcn_mfma_f32_16x16x32_bf16(ah, bh[1][kc], acc1, 0, 0, 0);
            acc1 = __builtin_amdgcn_mfma_f32_16x16x32_bf16(al, bh[1][kc], acc1, 0, 0, 0);
            acc1 = __builtin_amdgcn_mfma_f32_16x16x32_bf16(ah, bl[1][kc], acc1, 0, 0, 0);
        }
        float part[4];
#pragma unroll
        for (int r = 0; r < 4; ++r)
            part[r] = fmaxf(acc0[r] + b0, 0.f) * w0 + fmaxf(acc1[r] + b1, 0.f) * w1;
#pragma unroll
        for (int o = 1; o < 16; o <<= 1) {
#pragma unroll
            for (int r = 0; r < 4; ++r) part[r] += __shfl_xor(part[r], o);
        }
        if (row == 0) {
#pragma unroll
            for (int r = 0; r < 4; ++r) atomicAdd(&out[n0 + kb * 4 + r], part[r]);
        }
    }
}

extern "C" void kernel_launch(void* const* d_in, const int* in_sizes, int n_in,
                              void* d_out, int out_size, void* d_ws, size_t ws_size,
                              hipStream_t stream) {
    const float* x   = (const float*)d_in[0];
    const int*   ei  = (const int*)d_in[1];
    const float* Wl0 = (const float*)d_in[2];
    const float* bl0 = (const float*)d_in[3];
    const float* Wr0 = (const float*)d_in[4];
    const float* Wl1 = (const float*)d_in[5];
    const float* bl1 = (const float*)d_in[6];
    const float* Wr1 = (const float*)d_in[7];
    const float* Wl2 = (const float*)d_in[8];
    const float* bl2 = (const float*)d_in[9];
    const float* Wr2 = (const float*)d_in[10];
    const float* Wf  = (const float*)d_in[11];
    const float* bf  = (const float*)d_in[12];
    float* out = (float*)d_out;

    char* p = (char*)d_ws;
    auto alloc = [&](size_t n) { void* r = (void*)p; p += (n + 255) & ~(size_t)255; return r; };
    int*            hist      = (int*)alloc((size_t)NBLK * 256 * 4);
    int*            dbase     = (int*)alloc(257 * 4);
    int*            cnt       = (int*)alloc((size_t)NN * 4);
    int*            row_start = (int*)alloc((size_t)NN * 4);
    unsigned short* perm      = (unsigned short*)alloc((size_t)NE * 2);
    unsigned*       sbuf      = (unsigned*)alloc((size_t)NN * 128 * 4);
    unsigned*       hp        = (unsigned*)alloc((size_t)NN * 128 * 4);
    unsigned short* whi       = (unsigned short*)alloc((size_t)3 * 128 * 256 * 2);
    unsigned short* wlo       = (unsigned short*)alloc((size_t)3 * 128 * 256 * 2);
    unsigned*       packed    = sbuf;   // alias: consumed before first aggregate

    dim3 b256(256);
    // CSR build via bucket sort (no random global scatter, no global atomics)
    k_hist<<<dim3(NBLK), b256, 0, stream>>>(ei, hist);
    k_basescan<<<dim3(1), b256, 0, stream>>>(hist, dbase);
    k_scatter1<<<dim3(NBLK), b256, 0, stream>>>(ei, hist, packed);
    k_bucket_csr<<<dim3(NBUCK), b256, 0, stream>>>(packed, dbase, perm, cnt, row_start);

    // packing + out init
    k_pack_x<<<dim3((NN * 128 / 4 + 255) / 256), b256, 0, stream>>>(x, hp);
    k_pack_w<<<dim3(128), b256, 0, stream>>>(Wl0, Wr0, whi + 0 * 32768, wlo + 0 * 32768);
    k_pack_w<<<dim3(128), b256, 0, stream>>>(Wl1, Wr1, whi + 1 * 32768, wlo + 1 * 32768);
    k_pack_w<<<dim3(128), b256, 0, stream>>>(Wl2, Wr2, whi + 2 * 32768, wlo + 2 * 32768);
    k_init_out<<<dim3((NN + 255) / 256), b256, 0, stream>>>(out, bf);

    dim3 gAgg((NN + 3) / 4);    // 1 node/wave, 4 per block
    dim3 gGemm(512);            // 2 blocks/CU; grid-stride over 3125 tiles

    // layer 0
    k_aggregate<<<gAgg, b256, 0, stream>>>(hp, row_start, cnt, perm, sbuf);
    k_gemm_ws<<<gGemm, b256, 0, stream>>>(sbuf, hp, whi + 0 * 32768, wlo + 0 * 32768, bl0, hp);
    // layer 1 (in place)
    k_aggregate<<<gAgg, b256, 0, stream>>>(hp, row_start, cnt, perm, sbuf);
    k_gemm_ws<<<gGemm, b256, 0, stream>>>(sbuf, hp, whi + 1 * 32768, wlo + 1 * 32768, bl1, hp);
    // layer 2 + fused head
    k_aggregate<<<gAgg, b256, 0, stream>>>(hp, row_start, cnt, perm, sbuf);
    k_gemm_head<<<gGemm, b256, 0, stream>>>(sbuf, hp, whi + 2 * 32768, wlo + 2 * 32768, bl2, Wf, out);
}